// Round 1
// baseline (5615.399 us; speedup 1.0000x reference)
//
#include <hip/hip_runtime.h>
#include <hip/hip_bf16.h>

// BiRNN: T=512, B=64, NI=NH=512.
// out = [outputs (512*64*1024) | f_H (64*512) | b_H (64*512)] fp32.

#define T_ 512
#define B_ 64
#define NH_ 512

typedef __attribute__((ext_vector_type(8))) short short8;   // 8 bf16 = 4 VGPR (MFMA A/B frag)
typedef __attribute__((ext_vector_type(4))) float f32x4;    // MFMA C/D frag

#define AGENT __HIP_MEMORY_SCOPE_AGENT

static __device__ __forceinline__ unsigned short f2bf(float f) {
  unsigned int u = __builtin_bit_cast(unsigned int, f);
  u = (u + 0x7fffu + ((u >> 16) & 1u)) >> 16;   // RNE
  return (unsigned short)u;
}
static __device__ __forceinline__ float bf2f(unsigned short s) {
  return __builtin_bit_cast(float, ((unsigned int)s) << 16);
}

// ---------------------------------------------------------------------------
// Kernel 1: xw_d[t*64+b][n] = sum_i inputs[t*64+b][i] * W_xh_d[i][n]  (both dirs)
// Tile: 64 rows x 64 cols x K32 steps, bf16 MFMA, both weight mats share A tile.
// ---------------------------------------------------------------------------
__global__ __launch_bounds__(256, 2) void xw_gemm(
    const float* __restrict__ inp,       // [32768][512]
    const float* __restrict__ Wf,        // [512][512]
    const float* __restrict__ Wb,        // [512][512]
    unsigned short* __restrict__ xwf,    // [32768][512] bf16
    unsigned short* __restrict__ xwb) {
  __shared__ unsigned short As[64 * 40];   // [row][k] pad 40 vs bank conflicts
  __shared__ unsigned short Bfs[64 * 40];  // [n][k] (transposed in staging)
  __shared__ unsigned short Bbs[64 * 40];
  const int tid = threadIdx.x;
  const int w = tid >> 6, l = tid & 63;
  const int lr = l & 15, lg = l >> 4;
  const int rbase = blockIdx.x * 64;
  const int nbase = blockIdx.y * 64;

  f32x4 accf[4], accb[4];
#pragma unroll
  for (int tn = 0; tn < 4; ++tn) { accf[tn] = (f32x4){0,0,0,0}; accb[tn] = (f32x4){0,0,0,0}; }

  for (int i = 0; i < 16; ++i) {
    const int k0 = i * 32;
    __syncthreads();
    // stage A (64x32 fp32 -> bf16)
#pragma unroll
    for (int e = 0; e < 2; ++e) {
      int lin4 = tid + e * 256;               // 0..511 float4s
      int r = lin4 >> 3, c4 = (lin4 & 7) * 4;
      float4 v = *reinterpret_cast<const float4*>(&inp[(rbase + r) * 512 + k0 + c4]);
      unsigned short* dst = &As[r * 40 + c4];
      dst[0] = f2bf(v.x); dst[1] = f2bf(v.y); dst[2] = f2bf(v.z); dst[3] = f2bf(v.w);
    }
    // stage B, transposed to [n][k], both matrices
#pragma unroll
    for (int e = 0; e < 2; ++e) {
      int lin4 = tid + e * 256;               // 0..511
      int r = lin4 >> 4, c4 = (lin4 & 15) * 4; // r = k row, c4 = n col
      float4 vf = *reinterpret_cast<const float4*>(&Wf[(k0 + r) * 512 + nbase + c4]);
      float4 vb = *reinterpret_cast<const float4*>(&Wb[(k0 + r) * 512 + nbase + c4]);
      Bfs[(c4 + 0) * 40 + r] = f2bf(vf.x);
      Bfs[(c4 + 1) * 40 + r] = f2bf(vf.y);
      Bfs[(c4 + 2) * 40 + r] = f2bf(vf.z);
      Bfs[(c4 + 3) * 40 + r] = f2bf(vf.w);
      Bbs[(c4 + 0) * 40 + r] = f2bf(vb.x);
      Bbs[(c4 + 1) * 40 + r] = f2bf(vb.y);
      Bbs[(c4 + 2) * 40 + r] = f2bf(vb.z);
      Bbs[(c4 + 3) * 40 + r] = f2bf(vb.w);
    }
    __syncthreads();
    // compute: wave w owns rows w*16..+16
    const int ar = w * 16 + lr;
    const int kg = lg * 8;
    short8 a = *reinterpret_cast<const short8*>(&As[ar * 40 + kg]);
#pragma unroll
    for (int tn = 0; tn < 4; ++tn) {
      const int bc = tn * 16 + lr;
      short8 bf = *reinterpret_cast<const short8*>(&Bfs[bc * 40 + kg]);
      short8 bb = *reinterpret_cast<const short8*>(&Bbs[bc * 40 + kg]);
      accf[tn] = __builtin_amdgcn_mfma_f32_16x16x32_bf16(a, bf, accf[tn], 0, 0, 0);
      accb[tn] = __builtin_amdgcn_mfma_f32_16x16x32_bf16(a, bb, accb[tn], 0, 0, 0);
    }
  }
  // epilogue (C layout: col = l&15, row = (l>>4)*4 + q  [m89-verified])
#pragma unroll
  for (int tn = 0; tn < 4; ++tn)
#pragma unroll
    for (int q = 0; q < 4; ++q) {
      int row = rbase + w * 16 + lg * 4 + q;
      int col = nbase + tn * 16 + lr;
      xwf[row * 512 + col] = f2bf(accf[tn][q]);
      xwb[row * 512 + col] = f2bf(accb[tn][q]);
    }
}

// ---------------------------------------------------------------------------
// Kernel 2: persistent bidirectional scan.
// 32 WGs = 2 dirs x 4 row-groups(16 batch rows) x 4 col-groups(128 cols).
// Each of 4 waves/WG owns 32 cols: W_hh B-frags live in 128 VGPRs.
// Per step: exchange h (bf16) among the 4 col-partners of the row-group via
// global ping-pong buffer + per-(dir,rg,step) arrival counter (target 16 waves).
// ---------------------------------------------------------------------------
__global__ __launch_bounds__(256, 1) void birnn_scan(
    const float* __restrict__ Whf, const float* __restrict__ Whb,
    const float* __restrict__ bhf, const float* __restrict__ bhb,
    const unsigned short* __restrict__ xwf, const unsigned short* __restrict__ xwb,
    unsigned short* __restrict__ hx,   // [2 dir][2 parity][64][512] bf16
    unsigned int* __restrict__ cnt,    // [2][4][512]
    float* __restrict__ out) {
  const int bid = blockIdx.x;        // 0..31
  const int d  = bid >> 4;
  const int rg = (bid >> 2) & 3;
  const int cg = bid & 3;
  const int tid = threadIdx.x;
  const int w = tid >> 6, l = tid & 63;
  const int lr = l & 15, lg = l >> 4;
  const int cbase = cg * 128 + w * 32;
  const int rbase = rg * 16;

  const float* Wh = d ? Whb : Whf;
  const float* bh = d ? bhb : bhf;
  const unsigned short* xw = d ? xwb : xwf;
  unsigned int* mycnt = cnt + (d * 4 + rg) * 512;
  unsigned short* hxd = hx + d * (2 * 64 * 512);

  // Preload W_hh B-frags: frag(n,kk): col = cbase+n*16+(l&15), k = kk*32+(l>>4)*8+j.
  // Same k-slot bijection as A-frags => dot product correct for any true HW mapping.
  short8 wfr[2][16];
#pragma unroll
  for (int n = 0; n < 2; ++n) {
    const int col = cbase + n * 16 + lr;
#pragma unroll
    for (int kk = 0; kk < 16; ++kk) {
      const int kb = kk * 32 + lg * 8;
      short8 v;
#pragma unroll
      for (int j = 0; j < 8; ++j) v[j] = (short)f2bf(Wh[(kb + j) * 512 + col]);
      wfr[n][kk] = v;
    }
  }
  const float bias[2] = { bh[cbase + lr], bh[cbase + 16 + lr] };

  for (int s = 0; s < 512; ++s) {
    const int t = d ? (511 - s) : s;

    // prefetch xw for this step (independent of h -> hides L3 latency under poll)
    float xv[2][4];
#pragma unroll
    for (int n = 0; n < 2; ++n) {
      const int col = cbase + n * 16 + lr;
#pragma unroll
      for (int q = 0; q < 4; ++q) {
        const int b = rbase + lg * 4 + q;
        xv[n][q] = bf2f(__builtin_nontemporal_load(&xw[(t * 64 + b) * 512 + col]));
      }
    }

    f32x4 acc[2];
    acc[0] = (f32x4){0,0,0,0};
    acc[1] = (f32x4){0,0,0,0};

    if (s > 0) {
      if (l == 0) {  // one poller per wave
        while (__hip_atomic_load(&mycnt[s - 1], __ATOMIC_RELAXED, AGENT) < 16u)
          __builtin_amdgcn_s_sleep(1);
      }
      __threadfence();  // acquire: invalidate stale L1/L2 before reading partners' h
      const unsigned short* hsrc =
          hxd + ((s - 1) & 1) * (64 * 512) + (rbase + lr) * 512 + lg * 8;
      short8 af[16];
#pragma unroll
      for (int kk = 0; kk < 16; ++kk)
        af[kk] = *reinterpret_cast<const short8*>(hsrc + kk * 32);
#pragma unroll
      for (int kk = 0; kk < 16; ++kk) {
        acc[0] = __builtin_amdgcn_mfma_f32_16x16x32_bf16(af[kk], wfr[0][kk], acc[0], 0, 0, 0);
        acc[1] = __builtin_amdgcn_mfma_f32_16x16x32_bf16(af[kk], wfr[1][kk], acc[1], 0, 0, 0);
      }
    }

    // epilogue: h = tanh(xw + h@W + b); write outputs fp32 + exchange bf16
    unsigned short* hdst = hxd + (s & 1) * (64 * 512);
#pragma unroll
    for (int n = 0; n < 2; ++n) {
      const int col = cbase + n * 16 + lr;
#pragma unroll
      for (int q = 0; q < 4; ++q) {
        const int b = rbase + lg * 4 + q;
        float h = tanhf(xv[n][q] + acc[n][q] + bias[n]);
        __builtin_nontemporal_store(h, &out[(t * 64 + b) * 1024 + d * 512 + col]);
        if (s < 511) {
          hdst[b * 512 + col] = f2bf(h);
        } else {
          // final hidden state: f_H then b_H after the outputs block
          out[33554432 + d * 32768 + b * 512 + col] = h;
        }
      }
    }

    if (s < 511) {
      __threadfence();  // release: drain stores + L2 writeback before signaling
      if (l == 0)
        __hip_atomic_fetch_add(&mycnt[s], 1u, __ATOMIC_RELAXED, AGENT);
    }
  }
}

// ---------------------------------------------------------------------------
extern "C" void kernel_launch(void* const* d_in, const int* in_sizes, int n_in,
                              void* d_out, int out_size, void* d_ws, size_t ws_size,
                              hipStream_t stream) {
  (void)in_sizes; (void)n_in; (void)out_size; (void)ws_size;
  const float* inputs = (const float*)d_in[0];
  const float* W_xh_f = (const float*)d_in[1];
  const float* W_hh_f = (const float*)d_in[2];
  const float* b_h_f  = (const float*)d_in[3];
  const float* W_xh_b = (const float*)d_in[4];
  const float* W_hh_b = (const float*)d_in[5];
  const float* b_h_b  = (const float*)d_in[6];

  // workspace layout
  unsigned short* xwf = (unsigned short*)d_ws;            // 32768*512 bf16 = 33.5 MB
  unsigned short* xwb = xwf + 32768 * 512;                // 33.5 MB
  unsigned short* hx  = xwb + 32768 * 512;                // 2*2*64*512 bf16 = 256 KB
  unsigned int*   cnt = (unsigned int*)(hx + 2 * 2 * 64 * 512);  // 16 KB

  hipMemsetAsync(cnt, 0, 2 * 4 * 512 * sizeof(unsigned int), stream);

  dim3 g1(32768 / 64, 512 / 64), b1(256);
  xw_gemm<<<g1, b1, 0, stream>>>(inputs, W_xh_f, W_xh_b, xwf, xwb);

  birnn_scan<<<dim3(32), dim3(256), 0, stream>>>(
      W_hh_f, W_hh_b, b_h_f, b_h_b, xwf, xwb, hx, cnt, (float*)d_out);
}

// Round 3
// 3244.215 us; speedup vs baseline: 1.7309x; 1.7309x over previous
//
#include <hip/hip_runtime.h>
#include <hip/hip_bf16.h>

// BiRNN: T=512, B=64, NI=NH=512.
// out = [outputs (512*64*1024) | f_H (64*512) | b_H (64*512)] fp32.

#define T_ 512
#define B_ 64
#define NH_ 512

typedef __attribute__((ext_vector_type(8))) short short8;   // 8 bf16 = 4 VGPR (MFMA A/B frag)
typedef __attribute__((ext_vector_type(4))) float f32x4;    // MFMA C/D frag

#define AGENT __HIP_MEMORY_SCOPE_AGENT

static __device__ __forceinline__ unsigned short f2bf(float f) {
  unsigned int u = __builtin_bit_cast(unsigned int, f);
  u = (u + 0x7fffu + ((u >> 16) & 1u)) >> 16;   // RNE
  return (unsigned short)u;
}
static __device__ __forceinline__ float bf2f(unsigned short s) {
  return __builtin_bit_cast(float, ((unsigned int)s) << 16);
}

// ---------------------------------------------------------------------------
// Kernel 1: xw_d[t*64+b][n] = sum_i inputs[t*64+b][i] * W_xh_d[i][n]  (both dirs)
// Tile: 64 rows x 64 cols x K32 steps, bf16 MFMA, both weight mats share A tile.
// (unchanged — ~270us, optimize after scan is settled)
// ---------------------------------------------------------------------------
__global__ __launch_bounds__(256, 2) void xw_gemm(
    const float* __restrict__ inp,       // [32768][512]
    const float* __restrict__ Wf,        // [512][512]
    const float* __restrict__ Wb,        // [512][512]
    unsigned short* __restrict__ xwf,    // [32768][512] bf16
    unsigned short* __restrict__ xwb) {
  __shared__ unsigned short As[64 * 40];   // [row][k] pad 40 vs bank conflicts
  __shared__ unsigned short Bfs[64 * 40];  // [n][k] (transposed in staging)
  __shared__ unsigned short Bbs[64 * 40];
  const int tid = threadIdx.x;
  const int w = tid >> 6, l = tid & 63;
  const int lr = l & 15, lg = l >> 4;
  const int rbase = blockIdx.x * 64;
  const int nbase = blockIdx.y * 64;

  f32x4 accf[4], accb[4];
#pragma unroll
  for (int tn = 0; tn < 4; ++tn) { accf[tn] = (f32x4){0,0,0,0}; accb[tn] = (f32x4){0,0,0,0}; }

  for (int i = 0; i < 16; ++i) {
    const int k0 = i * 32;
    __syncthreads();
    // stage A (64x32 fp32 -> bf16)
#pragma unroll
    for (int e = 0; e < 2; ++e) {
      int lin4 = tid + e * 256;               // 0..511 float4s
      int r = lin4 >> 3, c4 = (lin4 & 7) * 4;
      float4 v = *reinterpret_cast<const float4*>(&inp[(rbase + r) * 512 + k0 + c4]);
      unsigned short* dst = &As[r * 40 + c4];
      dst[0] = f2bf(v.x); dst[1] = f2bf(v.y); dst[2] = f2bf(v.z); dst[3] = f2bf(v.w);
    }
    // stage B, transposed to [n][k], both matrices
#pragma unroll
    for (int e = 0; e < 2; ++e) {
      int lin4 = tid + e * 256;               // 0..511
      int r = lin4 >> 4, c4 = (lin4 & 15) * 4; // r = k row, c4 = n col
      float4 vf = *reinterpret_cast<const float4*>(&Wf[(k0 + r) * 512 + nbase + c4]);
      float4 vb = *reinterpret_cast<const float4*>(&Wb[(k0 + r) * 512 + nbase + c4]);
      Bfs[(c4 + 0) * 40 + r] = f2bf(vf.x);
      Bfs[(c4 + 1) * 40 + r] = f2bf(vf.y);
      Bfs[(c4 + 2) * 40 + r] = f2bf(vf.z);
      Bfs[(c4 + 3) * 40 + r] = f2bf(vf.w);
      Bbs[(c4 + 0) * 40 + r] = f2bf(vb.x);
      Bbs[(c4 + 1) * 40 + r] = f2bf(vb.y);
      Bbs[(c4 + 2) * 40 + r] = f2bf(vb.z);
      Bbs[(c4 + 3) * 40 + r] = f2bf(vb.w);
    }
    __syncthreads();
    // compute: wave w owns rows w*16..+16
    const int ar = w * 16 + lr;
    const int kg = lg * 8;
    short8 a = *reinterpret_cast<const short8*>(&As[ar * 40 + kg]);
#pragma unroll
    for (int tn = 0; tn < 4; ++tn) {
      const int bc = tn * 16 + lr;
      short8 bf = *reinterpret_cast<const short8*>(&Bfs[bc * 40 + kg]);
      short8 bb = *reinterpret_cast<const short8*>(&Bbs[bc * 40 + kg]);
      accf[tn] = __builtin_amdgcn_mfma_f32_16x16x32_bf16(a, bf, accf[tn], 0, 0, 0);
      accb[tn] = __builtin_amdgcn_mfma_f32_16x16x32_bf16(a, bb, accb[tn], 0, 0, 0);
    }
  }
  // epilogue (C layout: col = l&15, row = (l>>4)*4 + q  [m89-verified])
#pragma unroll
  for (int tn = 0; tn < 4; ++tn)
#pragma unroll
    for (int q = 0; q < 4; ++q) {
      int row = rbase + w * 16 + lg * 4 + q;
      int col = nbase + tn * 16 + lr;
      xwf[row * 512 + col] = f2bf(accf[tn][q]);
      xwb[row * 512 + col] = f2bf(accb[tn][q]);
    }
}

// ---------------------------------------------------------------------------
// Kernel 2: persistent bidirectional scan.
// 32 WGs = 2 dirs x 4 row-groups(16 batch rows) x 4 col-groups(128 cols).
// Each of 4 waves/WG owns 32 cols: W_hh B-frags live in 128 regs/lane.
// Cross-WG exchange: NO fences. All h traffic + flags use relaxed agent-scope
// atomics (sc1: complete at the coherent point, bypass non-coherent per-XCD L2).
// Producer order: h stores -> s_waitcnt vmcnt(0) -> per-wave flag store.
// Consumer: 64-lane ballot-poll over the 16 flag words, then atomic h loads
// (issued in program order after the poll -> fresh at the coherent point).
// ---------------------------------------------------------------------------
__global__ __launch_bounds__(256, 1) void birnn_scan(
    const float* __restrict__ Whf, const float* __restrict__ Whb,
    const float* __restrict__ bhf, const float* __restrict__ bhb,
    const unsigned short* __restrict__ xwf, const unsigned short* __restrict__ xwb,
    unsigned short* __restrict__ hx,   // [2 dir][2 parity][64][512] bf16
    unsigned int* __restrict__ flags,  // [2][4][16] per-wave step counters
    float* __restrict__ out) {
  const int bid = blockIdx.x;        // 0..31
  const int d  = bid >> 4;
  const int rg = (bid >> 2) & 3;
  const int cg = bid & 3;
  const int tid = threadIdx.x;
  const int w = tid >> 6, l = tid & 63;
  const int lr = l & 15, lg = l >> 4;
  const int cbase = cg * 128 + w * 32;
  const int rbase = rg * 16;

  const float* Wh = d ? Whb : Whf;
  const float* bh = d ? bhb : bhf;
  const unsigned short* xw = d ? xwb : xwf;
  unsigned int* myflags = flags + (d * 4 + rg) * 16;
  unsigned int* myflag  = myflags + cg * 4 + w;
  unsigned short* hxd = hx + d * (2 * 64 * 512);

  // Preload W_hh B-frags: frag(n,kk): col = cbase+n*16+(l&15), k = kk*32+(l>>4)*8+j.
  // Same k-slot bijection as A-frags => dot product correct for any true HW mapping.
  short8 wfr[2][16];
#pragma unroll
  for (int n = 0; n < 2; ++n) {
    const int col = cbase + n * 16 + lr;
#pragma unroll
    for (int kk = 0; kk < 16; ++kk) {
      const int kb = kk * 32 + lg * 8;
      short8 v;
#pragma unroll
      for (int j = 0; j < 8; ++j) v[j] = (short)f2bf(Wh[(kb + j) * 512 + col]);
      wfr[n][kk] = v;
    }
  }
  const float bias[2] = { bh[cbase + lr], bh[cbase + 16 + lr] };

  for (int s = 0; s < 512; ++s) {
    const int t = d ? (511 - s) : s;

    // prefetch xw for this step (independent of h -> hides latency under poll)
    float xv[2][4];
#pragma unroll
    for (int n = 0; n < 2; ++n) {
      const int col = cbase + n * 16 + lr;
#pragma unroll
      for (int q = 0; q < 4; ++q) {
        const int b = rbase + lg * 4 + q;
        xv[n][q] = bf2f(__builtin_nontemporal_load(&xw[(t * 64 + b) * 512 + col]));
      }
    }

    f32x4 acc[2];
    acc[0] = (f32x4){0,0,0,0};
    acc[1] = (f32x4){0,0,0,0};

    if (s > 0) {
      // all 64 lanes poll the 16 per-wave flags (4-way replicated) until all
      // partners have published step s (flag value s = completed step s-1).
      const unsigned int target = (unsigned int)s;
      while (true) {
        unsigned int v = __hip_atomic_load(&myflags[l & 15], __ATOMIC_RELAXED, AGENT);
        if (__ballot(v >= target) == ~0ull) break;
        __builtin_amdgcn_s_sleep(1);
      }
      asm volatile("" ::: "memory");  // don't let h loads hoist above the poll

      // A-frag kk covers k = kk*32 + lg*8 + j  ->  short-offset kk*32 from hsrc
      // (hsrc already includes lg*8)  ->  u64-offset kk*8 (+1 for the 2nd qword).
      const unsigned long long* hsrc64 = reinterpret_cast<const unsigned long long*>(
          hxd + ((s - 1) & 1) * (64 * 512) + (rbase + lr) * 512 + lg * 8);
      short8 af[16];
#pragma unroll
      for (int kk = 0; kk < 16; ++kk) {
        union { unsigned long long q[2]; short8 v; } u;
        u.q[0] = __hip_atomic_load(&hsrc64[kk * 8 + 0], __ATOMIC_RELAXED, AGENT);
        u.q[1] = __hip_atomic_load(&hsrc64[kk * 8 + 1], __ATOMIC_RELAXED, AGENT);
        af[kk] = u.v;
      }
#pragma unroll
      for (int kk = 0; kk < 16; ++kk) {
        acc[0] = __builtin_amdgcn_mfma_f32_16x16x32_bf16(af[kk], wfr[0][kk], acc[0], 0, 0, 0);
        acc[1] = __builtin_amdgcn_mfma_f32_16x16x32_bf16(af[kk], wfr[1][kk], acc[1], 0, 0, 0);
      }
    }

    // h = tanh(xw + h@W + b)
    float hval[2][4];
#pragma unroll
    for (int n = 0; n < 2; ++n)
#pragma unroll
      for (int q = 0; q < 4; ++q)
        hval[n][q] = tanhf(xv[n][q] + acc[n][q] + bias[n]);

    // publish h for partners (bf16, packed u32, agent-scope -> coherent point)
    if (s < 511) {
      unsigned int* hdst32 = reinterpret_cast<unsigned int*>(
          hxd + (s & 1) * (64 * 512));
#pragma unroll
      for (int n = 0; n < 2; ++n) {
        const int col = cbase + n * 16 + lr;
#pragma unroll
        for (int q = 0; q < 4; ++q) {
          const int b = rbase + lg * 4 + q;
          unsigned short hv = f2bf(hval[n][q]);
          int partner = __shfl_xor((int)hv, 1);          // all lanes participate
          if (!(l & 1)) {
            unsigned int packed = (unsigned int)hv |
                                  (((unsigned int)partner & 0xffffu) << 16);
            __hip_atomic_store(&hdst32[(b * 512 + col) >> 1], packed,
                               __ATOMIC_RELAXED, AGENT);
          }
        }
      }
      // order: h stores acked at coherent point, THEN signal
      asm volatile("s_waitcnt vmcnt(0)" ::: "memory");
      if (l == 0)
        __hip_atomic_store(myflag, (unsigned int)(s + 1), __ATOMIC_RELAXED, AGENT);
    }

    // fp32 outputs — off the critical path (after the signal)
#pragma unroll
    for (int n = 0; n < 2; ++n) {
      const int col = cbase + n * 16 + lr;
#pragma unroll
      for (int q = 0; q < 4; ++q) {
        const int b = rbase + lg * 4 + q;
        __builtin_nontemporal_store(hval[n][q],
                                    &out[(t * 64 + b) * 1024 + d * 512 + col]);
        if (s == 511)  // final hidden state: f_H then b_H after outputs block
          out[33554432 + d * 32768 + b * 512 + col] = hval[n][q];
      }
    }
  }
}

// ---------------------------------------------------------------------------
extern "C" void kernel_launch(void* const* d_in, const int* in_sizes, int n_in,
                              void* d_out, int out_size, void* d_ws, size_t ws_size,
                              hipStream_t stream) {
  (void)in_sizes; (void)n_in; (void)out_size; (void)ws_size;
  const float* inputs = (const float*)d_in[0];
  const float* W_xh_f = (const float*)d_in[1];
  const float* W_hh_f = (const float*)d_in[2];
  const float* b_h_f  = (const float*)d_in[3];
  const float* W_xh_b = (const float*)d_in[4];
  const float* W_hh_b = (const float*)d_in[5];
  const float* b_h_b  = (const float*)d_in[6];

  // workspace layout
  unsigned short* xwf = (unsigned short*)d_ws;            // 32768*512 bf16 = 33.5 MB
  unsigned short* xwb = xwf + 32768 * 512;                // 33.5 MB
  unsigned short* hx  = xwb + 32768 * 512;                // 2*2*64*512 bf16 = 256 KB
  unsigned int* flags = (unsigned int*)(hx + 2 * 2 * 64 * 512);  // 512 B

  hipMemsetAsync(flags, 0, 2 * 4 * 16 * sizeof(unsigned int), stream);

  dim3 g1(32768 / 64, 512 / 64), b1(256);
  xw_gemm<<<g1, b1, 0, stream>>>(inputs, W_xh_f, W_xh_b, xwf, xwb);

  birnn_scan<<<dim3(32), dim3(256), 0, stream>>>(
      W_hh_f, W_hh_b, b_h_f, b_h_b, xwf, xwb, hx, flags, (float*)d_out);
}